// Round 7
// baseline (581.815 us; speedup 1.0000x reference)
//
#include <hip/hip_runtime.h>
#include <cstdint>

// MatrixReLU via matrix-sign Newton-Schulz, 1 wave = 1 matrix, 32x32x16 MFMA.
//   out = 0.5X + 0.5*eps*I + 0.5*|B|,  B = X - eps*I,  |B| = B*sign(B)
// sign: 4 quintic (Y <- Y*(qa*I + qb*Z + qc*Z^2), Z=Y^2) + 3 cubic (Y*(1.5I-0.5Z)).
// bf16 2-term split products (drop l*l term). Symmetric operands => A-frags
// serve as B-frags (same lane mapping). No __syncthreads anywhere (wave-local).
// 4 matrices/block (1 per wave), 32KB LDS each, launch_bounds(256,1) -> VGPR-free.

#define EPSV 1e-4f

typedef short bf16x8  __attribute__((ext_vector_type(8)));
typedef short short4v __attribute__((ext_vector_type(4)));
typedef float f32x16  __attribute__((ext_vector_type(16)));

__device__ __forceinline__ short f2bf(float f) {            // RNE fp32->bf16
  unsigned u = __float_as_uint(f);
  return (short)((u + 0x7FFFu + ((u >> 16) & 1u)) >> 16);
}
__device__ __forceinline__ float bf2f(short s) {
  return __uint_as_float(((unsigned)(unsigned short)s) << 16);
}
__device__ __forceinline__ int swz(int row, int byte) { return byte ^ ((row & 7) << 4); }
__device__ __forceinline__ void fence() { __asm volatile("" ::: "memory"); }

struct Frags { bf16x8 f[2][4]; };   // [mi][ks]: row=32*mi+(l&31), k=16*ks+8*(l>>5)+j

__device__ __forceinline__ void loadFrags(const short* buf, int l31, int h, Frags& F) {
  #pragma unroll
  for (int mi = 0; mi < 2; mi++)
    #pragma unroll
    for (int ks = 0; ks < 4; ks++) {
      const int row = 32 * mi + l31;
      F.f[mi][ks] = *(const bf16x8*)((const char*)buf + swz(row, row * 128 + 32 * ks + 16 * h));
    }
}

// acc = Ah*Bh + Ah*Bl + Al*Bh  (2-term split product, fp32 accumulate)
__device__ __forceinline__ void chains3(const Frags& Ah, const Frags& Al,
                                        const Frags& Bh, const Frags& Bl,
                                        f32x16 acc[2][2]) {
  #pragma unroll
  for (int mi = 0; mi < 2; mi++)
    #pragma unroll
    for (int ni = 0; ni < 2; ni++)
      #pragma unroll
      for (int e = 0; e < 16; e++) acc[mi][ni][e] = 0.f;
#define MM(A, B) acc[mi][ni] = __builtin_amdgcn_mfma_f32_32x32x16_bf16(A, B, acc[mi][ni], 0, 0, 0)
  #pragma unroll
  for (int ks = 0; ks < 4; ks++) {
    #pragma unroll
    for (int mi = 0; mi < 2; mi++)
      #pragma unroll
      for (int ni = 0; ni < 2; ni++) MM(Ah.f[mi][ks], Bh.f[ni][ks]);
    #pragma unroll
    for (int mi = 0; mi < 2; mi++)
      #pragma unroll
      for (int ni = 0; ni < 2; ni++) MM(Ah.f[mi][ks], Bl.f[ni][ks]);
    #pragma unroll
    for (int mi = 0; mi < 2; mi++)
      #pragma unroll
      for (int ni = 0; ni < 2; ni++) MM(Al.f[mi][ks], Bh.f[ni][ks]);
  }
#undef MM
}

// write acc (scaled) transposed (== true positions, result symmetric) as bf16 h/l
__device__ __forceinline__ void writeCT(short* bh, short* bl, const f32x16 acc[2][2],
                                        int l31, int h, float scale) {
  #pragma unroll
  for (int mi = 0; mi < 2; mi++)
    #pragma unroll
    for (int ni = 0; ni < 2; ni++) {
      const int R = 32 * ni + l31;              // transposed row = C col
      #pragma unroll
      for (int q = 0; q < 4; q++) {
        short4v hv, lv;
        #pragma unroll
        for (int p = 0; p < 4; p++) {
          float v = acc[mi][ni][4 * q + p] * scale;
          short hh = f2bf(v);
          hv[p] = hh;
          lv[p] = f2bf(v - bf2f(hh));
        }
        const int off = swz(R, R * 128 + (32 * mi + 8 * q + 4 * h) * 2);
        *(short4v*)((char*)bh + off) = hv;
        *(short4v*)((char*)bl + off) = lv;
      }
    }
}

__global__ __launch_bounds__(256, 1) void mrelu_w(const float* __restrict__ X,
                                                  float* __restrict__ O, int nmat) {
  __shared__ short lds[4][16384];   // per wave: Yh, Yl, Zh/Vh, Zl/Vl (4096 shorts each)
  const int t = threadIdx.x, wid = t >> 6, l = t & 63;
  const int l31 = l & 31, h = l >> 5;
  const int mat = blockIdx.x * 4 + wid;
  if (mat >= nmat) return;
  const float* Xb = X + (size_t)mat * 4096;
  short* Yh = &lds[wid][0];
  short* Yl = Yh + 4096;
  short* Zh = Yh + 8192;
  short* Zl = Yh + 12288;

  // ---- load X, B = X - eps*I, ||B||_F^2 (wave-local reduce) ----
  float4 xv[16];
  float ssq = 0.f;
  #pragma unroll
  for (int q = 0; q < 16; q++) {
    float4 v = reinterpret_cast<const float4*>(Xb)[l + 64 * q];
    const int e = 4 * l + 256 * q, row = e >> 6, col = e & 63, d = row - col;
    if (d >= 0 && d < 4) (&v.x)[d] -= EPSV;
    ssq += v.x * v.x + v.y * v.y + v.z * v.z + v.w * v.w;
    xv[q] = v;
  }
  #pragma unroll
  for (int o = 32; o >= 1; o >>= 1) ssq += __shfl_xor(ssq, o, 64);
  const float S0 = sqrtf(ssq) + 1e-30f;
  const float invS0 = 1.0f / S0;

  // ---- write Y0 = B/S0 as bf16 h/l ----
  #pragma unroll
  for (int q = 0; q < 16; q++) {
    const int e = 4 * l + 256 * q, row = e >> 6, col = e & 63;
    short4v hv, lv;
    #pragma unroll
    for (int i = 0; i < 4; i++) {
      float v = (&xv[q].x)[i] * invS0;
      short hh = f2bf(v);
      hv[i] = hh;
      lv[i] = f2bf(v - bf2f(hh));
    }
    const int off = swz(row, row * 128 + col * 2);
    *(short4v*)((char*)Yh + off) = hv;
    *(short4v*)((char*)Yl + off) = lv;
  }
  fence();

  Frags FA, FB, FC, FD;
  f32x16 accA[2][2], accB[2][2];

  // ---- Z0 = Y0^2; r = ||Z0||_F^(1/2) >= mu_max; lam = 1/r ----
  loadFrags(Yh, l31, h, FA);
  loadFrags(Yl, l31, h, FB);
  chains3(FA, FB, FA, FB, accA);
  float zss = 0.f;
  #pragma unroll
  for (int mi = 0; mi < 2; mi++)
    #pragma unroll
    for (int ni = 0; ni < 2; ni++)
      #pragma unroll
      for (int e = 0; e < 16; e++) zss += accA[mi][ni][e] * accA[mi][ni][e];
  #pragma unroll
  for (int o = 32; o >= 1; o >>= 1) zss += __shfl_xor(zss, o, 64);
  const float rr = sqrtf(sqrtf(zss + 1e-30f));
  float lam = 1.0f / rr;
  const float lam2 = lam * lam;
  #pragma unroll
  for (int mi = 0; mi < 2; mi++)
    #pragma unroll
    for (int ni = 0; ni < 2; ni++)
      #pragma unroll
      for (int e = 0; e < 16; e++) accA[mi][ni][e] *= lam2;   // Z true units
  writeCT(Zh, Zl, accA, l31, h, 1.0f);
  fence();

  const float qa = 3.4445f, qb = -4.7750f, qc = 2.0315f;

  // ---- 4 quintic steps ----
  #pragma unroll 1
  for (int it = 0; it < 4; it++) {
    if (it > 0) {                                  // refresh Z = Y^2 (accA = Zc)
      loadFrags(Yh, l31, h, FA);
      loadFrags(Yl, l31, h, FB);
      chains3(FA, FB, FA, FB, accA);
      writeCT(Zh, Zl, accA, l31, h, 1.0f);
      fence();
    }
    loadFrags(Zh, l31, h, FC);                     // Z frags
    loadFrags(Zl, l31, h, FD);
    chains3(FC, FD, FC, FD, accB);                 // Z^2
    #pragma unroll
    for (int mi = 0; mi < 2; mi++)
      #pragma unroll
      for (int ni = 0; ni < 2; ni++)
        #pragma unroll
        for (int r = 0; r < 16; r++) {             // V = qc*Z^2 + qb*Z + qa*I
          const int grow = 32 * mi + (r & 3) + 8 * (r >> 2) + 4 * h;
          const int gcol = 32 * ni + l31;
          accB[mi][ni][r] = qc * accB[mi][ni][r] + qb * accA[mi][ni][r] +
                            ((grow == gcol) ? qa : 0.f);
        }
    writeCT(Zh, Zl, accB, l31, h, 1.0f);           // V overwrites Z buffer
    fence();
    loadFrags(Yh, l31, h, FA);
    loadFrags(Yl, l31, h, FB);
    loadFrags(Zh, l31, h, FC);                     // V frags
    loadFrags(Zl, l31, h, FD);
    chains3(FA, FB, FC, FD, accA);                 // Ynew = Y*V
    writeCT(Yh, Yl, accA, l31, h, lam);            // fold lam (first iter only)
    lam = 1.0f;
    fence();
  }

  // ---- 3 cubic steps: Y <- Y*(1.5I - 0.5*Y^2) ----
  #pragma unroll 1
  for (int it = 0; it < 3; it++) {
    loadFrags(Yh, l31, h, FA);
    loadFrags(Yl, l31, h, FB);
    chains3(FA, FB, FA, FB, accA);                 // Y^2
    #pragma unroll
    for (int mi = 0; mi < 2; mi++)
      #pragma unroll
      for (int ni = 0; ni < 2; ni++)
        #pragma unroll
        for (int r = 0; r < 16; r++) {
          const int grow = 32 * mi + (r & 3) + 8 * (r >> 2) + 4 * h;
          const int gcol = 32 * ni + l31;
          accA[mi][ni][r] = ((grow == gcol) ? 1.5f : 0.f) - 0.5f * accA[mi][ni][r];
        }
    writeCT(Zh, Zl, accA, l31, h, 1.0f);           // V
    fence();
    loadFrags(Zh, l31, h, FC);
    loadFrags(Zl, l31, h, FD);
    chains3(FA, FB, FC, FD, accB);                 // Y*V (Y frags kept in regs)
    writeCT(Yh, Yl, accB, l31, h, 1.0f);
    fence();
  }

  // ---- final: P = B*sign, out = 0.5X + 0.5*eps*I + 0.5*P ----
  loadFrags(Yh, l31, h, FA);
  loadFrags(Yl, l31, h, FB);
  #pragma unroll
  for (int mi = 0; mi < 2; mi++)
    #pragma unroll
    for (int ks = 0; ks < 4; ks++) {               // B frags straight from global X
      const int row = 32 * mi + l31;
      const int k0 = 16 * ks + 8 * h;
      float4 a = *reinterpret_cast<const float4*>(&Xb[row * 64 + k0]);
      float4 b = *reinterpret_cast<const float4*>(&Xb[row * 64 + k0 + 4]);
      bf16x8 hh, ll;
      #pragma unroll
      for (int j = 0; j < 8; j++) {
        float v = (j < 4) ? (&a.x)[j] : (&b.x)[j - 4];
        if (row == k0 + j) v -= EPSV;
        short hb = f2bf(v);
        hh[j] = hb;
        ll[j] = f2bf(v - bf2f(hb));
      }
      FC.f[mi][ks] = hh;
      FD.f[mi][ks] = ll;
    }
  chains3(FC, FD, FA, FB, accA);                   // B*Y = |B| (approx)
  float* Ob = O + (size_t)mat * 4096;
  #pragma unroll
  for (int mi = 0; mi < 2; mi++)
    #pragma unroll
    for (int ni = 0; ni < 2; ni++) {
      const int R = 32 * ni + l31;
      #pragma unroll
      for (int q = 0; q < 4; q++) {
        const int cb = 32 * mi + 8 * q + 4 * h;
        float4 x = *reinterpret_cast<const float4*>(&Xb[R * 64 + cb]);
        float4 o;
        #pragma unroll
        for (int p = 0; p < 4; p++)
          (&o.x)[p] = 0.5f * (&x.x)[p] + 0.5f * accA[mi][ni][4 * q + p] +
                      ((R == cb + p) ? 0.5f * EPSV : 0.f);
        *reinterpret_cast<float4*>(&Ob[R * 64 + cb]) = o;
      }
    }
}

extern "C" void kernel_launch(void* const* d_in, const int* in_sizes, int n_in,
                              void* d_out, int out_size, void* d_ws, size_t ws_size,
                              hipStream_t stream) {
  const float* X = (const float*)d_in[0];
  float* O = (float*)d_out;
  const int nmat = in_sizes[0] >> 12;
  const int blocks = (nmat + 3) / 4;
  mrelu_w<<<blocks, 256, 0, stream>>>(X, O, nmat);
}

// Round 8
// 481.216 us; speedup vs baseline: 1.2091x; 1.2091x over previous
//
#include <hip/hip_runtime.h>
#include <cstdint>

// MatrixReLU via matrix-sign Newton-Schulz, 1 wave = 1 matrix, 32x32x16 MFMA,
// ZERO LDS: symmetric C-layout -> fragment conversion done in-register with
// shfl_xor(32) half-exchange. bf16 2-term split products (drop l*l).
//   out = 0.5X + 0.5*eps*I + 0.5*|B|,  B = X - eps*I,  |B| = B*sign(B)
// sign: 4 quintic Y<-Y*(qa I + qb Z + qc Z^2), Z=Y^2; then 3 cubic Y<-Y*(1.5I-0.5Z).
// 4 waves/block, no shared memory -> 2 waves/SIMD at <=256 VGPR (TLP restored).

#define EPSV 1e-4f

typedef short bf16x8  __attribute__((ext_vector_type(8)));
typedef float f32x16  __attribute__((ext_vector_type(16)));

__device__ __forceinline__ short f2bf(float f) {            // RNE fp32->bf16
  unsigned u = __float_as_uint(f);
  return (short)((u + 0x7FFFu + ((u >> 16) & 1u)) >> 16);
}
__device__ __forceinline__ float bf2f(short s) {
  return __uint_as_float(((unsigned)(unsigned short)s) << 16);
}

// Fragment set for one symmetric 64x64 matrix, h/l bf16 split.
// h[mi][ks], l[mi][ks]: lane (h=l>>5, l31=l&31) holds M[32*mi+l31][16*ks+8*h+j], j=0..7.
// By symmetry the same registers serve as MFMA A-frags (row-major) AND B-frags.
struct FragSet { bf16x8 h[2][4]; bf16x8 l[2][4]; };   // 64 VGPR

// acc[mi][ni] += A*B with 2-term split: Ah*Bh + Ah*Bl + Al*Bh (fp32 accum).
__device__ __forceinline__ void mmAcc(const FragSet& A, const FragSet& B, f32x16 acc[2][2]) {
  #pragma unroll
  for (int mi = 0; mi < 2; mi++)
    #pragma unroll
    for (int ni = 0; ni < 2; ni++)
      #pragma unroll
      for (int e = 0; e < 16; e++) acc[mi][ni][e] = 0.f;
#define MM(Af, Bf) acc[mi][ni] = __builtin_amdgcn_mfma_f32_32x32x16_bf16(Af, Bf, acc[mi][ni], 0, 0, 0)
  #pragma unroll
  for (int ks = 0; ks < 4; ks++) {
    #pragma unroll
    for (int mi = 0; mi < 2; mi++)
      #pragma unroll
      for (int ni = 0; ni < 2; ni++) MM(A.h[mi][ks], B.h[ni][ks]);
    #pragma unroll
    for (int mi = 0; mi < 2; mi++)
      #pragma unroll
      for (int ni = 0; ni < 2; ni++) MM(A.h[mi][ks], B.l[ni][ks]);
    #pragma unroll
    for (int mi = 0; mi < 2; mi++)
      #pragma unroll
      for (int ni = 0; ni < 2; ni++) MM(A.l[mi][ks], B.h[ni][ks]);
  }
#undef MM
}

// Convert C-layout acc of a SYMMETRIC result into FragSet (h/l split), in-register.
// v = acc*scale (+ diag on the diagonal) (+ zc * Zadd if ADDZ). out may alias Zadd.
// Derivation (verified against the LDS writeCT/loadFrags pair):
//   target F[ni][2*mi+ksp] j: j=p   <- h_s=0 lane's acc[mi][ni][8ksp+4*h_t+p]
//                             j=4+p <- h_s=1 lane's acc[mi][ni][8ksp+4*h_t+p]
// so each lane keeps a_lo/a_hi and half-exchanges with lane^32.
template <bool ADDZ>
__device__ __forceinline__ void convSplit(const f32x16 acc[2][2], float scale, float diag,
                                          const FragSet* Zadd, float zc,
                                          int l31, int h, FragSet& out) {
  #pragma unroll
  for (int mi = 0; mi < 2; mi++)
    #pragma unroll
    for (int ni = 0; ni < 2; ni++)
      #pragma unroll
      for (int ksp = 0; ksp < 2; ksp++) {
        const int ks = 2 * mi + ksp;
        const int row = 32 * ni + l31;
        const int col0 = 16 * ks + 8 * h;           // + j
        float v[8];
        #pragma unroll
        for (int p = 0; p < 4; p++) {
          float a_lo = acc[mi][ni][8 * ksp + p];
          float a_hi = acc[mi][ni][8 * ksp + 4 + p];
          float sendv = h ? a_lo : a_hi;
          float recv = __shfl_xor(sendv, 32, 64);
          v[p]     = h ? recv : a_lo;               // j = p
          v[4 + p] = h ? a_hi : recv;               // j = 4+p
        }
        bf16x8 fh, fl;
        #pragma unroll
        for (int j = 0; j < 8; j++) {
          float w = v[j] * scale + ((row == col0 + j) ? diag : 0.f);
          if (ADDZ) w += zc * (bf2f(Zadd->h[ni][ks][j]) + bf2f(Zadd->l[ni][ks][j]));
          short hh = f2bf(w);
          fh[j] = hh;
          fl[j] = f2bf(w - bf2f(hh));
        }
        out.h[ni][ks] = fh;
        out.l[ni][ks] = fl;
      }
}

__global__ __launch_bounds__(256, 2) void mrelu_r(const float* __restrict__ X,
                                                  float* __restrict__ O, int nmat) {
  const int t = threadIdx.x, wid = t >> 6, l = t & 63;
  const int l31 = l & 31, h = l >> 5;
  const int mat = blockIdx.x * 4 + wid;
  if (mat >= nmat) return;
  const float* Xb = X + (size_t)mat * 4096;

  FragSet Y, T;
  f32x16 acc[2][2];

  // ---- load B = X - eps*I directly at fragment positions; ||B||_F^2 ----
  float xv[2][4][8];
  float ssq = 0.f;
  #pragma unroll
  for (int mi = 0; mi < 2; mi++)
    #pragma unroll
    for (int ks = 0; ks < 4; ks++) {
      const int row = 32 * mi + l31;
      const int col0 = 16 * ks + 8 * h;
      float4 a = *reinterpret_cast<const float4*>(&Xb[row * 64 + col0]);
      float4 b = *reinterpret_cast<const float4*>(&Xb[row * 64 + col0 + 4]);
      #pragma unroll
      for (int j = 0; j < 8; j++) {
        float v = (j < 4) ? (&a.x)[j] : (&b.x)[j - 4];
        if (row == col0 + j) v -= EPSV;
        xv[mi][ks][j] = v;
        ssq += v * v;
      }
    }
  #pragma unroll
  for (int o = 32; o >= 1; o >>= 1) ssq += __shfl_xor(ssq, o, 64);
  const float invS0 = 1.0f / (sqrtf(ssq) + 1e-30f);

  // ---- Y0 = B/S0 frags (h/l split) ----
  #pragma unroll
  for (int mi = 0; mi < 2; mi++)
    #pragma unroll
    for (int ks = 0; ks < 4; ks++) {
      bf16x8 fh, fl;
      #pragma unroll
      for (int j = 0; j < 8; j++) {
        float v = xv[mi][ks][j] * invS0;
        short hh = f2bf(v);
        fh[j] = hh;
        fl[j] = f2bf(v - bf2f(hh));
      }
      Y.h[mi][ks] = fh;
      Y.l[mi][ks] = fl;
    }

  // ---- Z0 = Y0^2; r = ||Z0||_F^(1/2) >= mu_max; lam = 1/r ----
  mmAcc(Y, Y, acc);
  float zss = 0.f;
  #pragma unroll
  for (int mi = 0; mi < 2; mi++)
    #pragma unroll
    for (int ni = 0; ni < 2; ni++)
      #pragma unroll
      for (int e = 0; e < 16; e++) zss += acc[mi][ni][e] * acc[mi][ni][e];
  #pragma unroll
  for (int o = 32; o >= 1; o >>= 1) zss += __shfl_xor(zss, o, 64);
  const float rr = sqrtf(sqrtf(zss + 1e-30f));
  float lam = 1.0f / rr;
  convSplit<false>(acc, lam * lam, 0.f, nullptr, 0.f, l31, h, T);   // T := Z (true units)

  const float qa = 3.4445f, qb = -4.7750f, qc = 2.0315f;

  // ---- 4 quintic steps: Y <- Y*(qa I + qb Z + qc Z^2) ----
  #pragma unroll 1
  for (int it = 0; it < 4; it++) {
    if (it > 0) {
      mmAcc(Y, Y, acc);                                             // Z = Y^2
      convSplit<false>(acc, 1.f, 0.f, nullptr, 0.f, l31, h, T);     // T := Z
    }
    mmAcc(T, T, acc);                                               // Z^2
    convSplit<true>(acc, qc, qa, &T, qb, l31, h, T);                // T := V
    mmAcc(Y, T, acc);                                               // Y*V
    convSplit<false>(acc, lam, 0.f, nullptr, 0.f, l31, h, Y);       // Y := Ynew (lam folds once)
    lam = 1.0f;
  }

  // ---- 3 cubic steps: Y <- Y*(1.5I - 0.5*Y^2) ----
  #pragma unroll 1
  for (int it = 0; it < 3; it++) {
    mmAcc(Y, Y, acc);                                               // Y^2
    convSplit<false>(acc, -0.5f, 1.5f, nullptr, 0.f, l31, h, T);    // T := V
    mmAcc(Y, T, acc);                                               // Y*V
    convSplit<false>(acc, 1.f, 0.f, nullptr, 0.f, l31, h, Y);       // Y := Ynew
  }

  // ---- final: P = B*sign(B); out = 0.5X + 0.5*eps*I + 0.5*P ----
  #pragma unroll
  for (int mi = 0; mi < 2; mi++)
    #pragma unroll
    for (int ks = 0; ks < 4; ks++) {                                // B frags from global
      const int row = 32 * mi + l31;
      const int col0 = 16 * ks + 8 * h;
      float4 a = *reinterpret_cast<const float4*>(&Xb[row * 64 + col0]);
      float4 b = *reinterpret_cast<const float4*>(&Xb[row * 64 + col0 + 4]);
      bf16x8 fh, fl;
      #pragma unroll
      for (int j = 0; j < 8; j++) {
        float v = (j < 4) ? (&a.x)[j] : (&b.x)[j - 4];
        if (row == col0 + j) v -= EPSV;
        short hh = f2bf(v);
        fh[j] = hh;
        fl[j] = f2bf(v - bf2f(hh));
      }
      T.h[mi][ks] = fh;
      T.l[mi][ks] = fl;
    }
  mmAcc(T, Y, acc);                                                 // B*sign
  float* Ob = O + (size_t)mat * 4096;
  #pragma unroll
  for (int mi = 0; mi < 2; mi++)
    #pragma unroll
    for (int ni = 0; ni < 2; ni++) {
      const int R = 32 * ni + l31;                                  // transposed store
      #pragma unroll
      for (int q = 0; q < 4; q++) {
        const int cb = 32 * mi + 8 * q + 4 * h;
        float4 x = *reinterpret_cast<const float4*>(&Xb[R * 64 + cb]);
        float4 o;
        #pragma unroll
        for (int p = 0; p < 4; p++)
          (&o.x)[p] = 0.5f * (&x.x)[p] + 0.5f * acc[mi][ni][4 * q + p] +
                      ((R == cb + p) ? 0.5f * EPSV : 0.f);
        *reinterpret_cast<float4*>(&Ob[R * 64 + cb]) = o;
      }
    }
}

extern "C" void kernel_launch(void* const* d_in, const int* in_sizes, int n_in,
                              void* d_out, int out_size, void* d_ws, size_t ws_size,
                              hipStream_t stream) {
  const float* X = (const float*)d_in[0];
  float* O = (float*)d_out;
  const int nmat = in_sizes[0] >> 12;
  const int blocks = (nmat + 3) / 4;
  mrelu_r<<<blocks, 256, 0, stream>>>(X, O, nmat);
}